// Round 6
// baseline (295.761 us; speedup 1.0000x reference)
//
#include <hip/hip_runtime.h>
#include <hip/hip_bf16.h>
#include <cstdint>

#define NN 50000
#define NE 1200000
#define DD 128
#define RR 6
#define NEG 0.2f
#define NB 196          // ceil(NN/256) buckets of 256 nodes
#define TILE 4096       // edges per k_bscatter block
#define KS2 24          // K-slices for gemm2 (768/32)

typedef __hip_bfloat16 bf16;
typedef __attribute__((ext_vector_type(8))) short short8;
typedef __attribute__((ext_vector_type(4))) float f32x4;

__device__ __forceinline__ float bflo(unsigned u) { return __uint_as_float((u & 0xFFFFu) << 16); }
__device__ __forceinline__ float bfhi(unsigned u) { return __uint_as_float(u & 0xFFFF0000u); }
__device__ __forceinline__ ushort f2b(float v) {  // f32 -> bf16 RTNE
  unsigned b = __float_as_uint(v);
  return (ushort)((b + 0x7FFFu + ((b >> 16) & 1u)) >> 16);
}

// ------- prep: bcnt zero + wq/wk + pack W_cat[768][128] into B-frags -------
__global__ __launch_bounds__(256) void k_prep(const float* __restrict__ W,
    const float* __restrict__ qv, const float* __restrict__ kv,
    float* __restrict__ wq, float* __restrict__ wk,
    ushort* __restrict__ wp2, int* __restrict__ bcnt) {
  int t = blockIdx.x * 256 + threadIdx.x;
  if (t < NB) bcnt[t] = 0;
  if (t < RR * DD) {
    int r = t / DD, d = t % DD;
    const float* row = W + ((size_t)r * DD + d) * DD;
    float aq = 0.f, ak = 0.f;
    for (int o = 0; o < DD; ++o) { float w = row[o]; aq += w * qv[o]; ak += w * kv[o]; }
    wq[t] = aq; wk[t] = ak;
  }
  if (t < 8 * KS2 * 64) {   // 12288 threads: one B-fragment 8-elem record each
    int lane = t & 63;
    int g = t >> 6;
    int ks = g % KS2, cf = g / KS2;
    int col = cf * 16 + (lane & 15);
    int k0 = ks * 32 + (lane >> 4) * 8;
    ushort* dst = wp2 + (size_t)t * 8;
    #pragma unroll
    for (int e = 0; e < 8; ++e)
      dst[e] = f2b(W[(size_t)(k0 + e) * DD + col]);   // W viewed as [768][128]
  }
}

// ------- nq/nk per node (+ bf16 copy of x), one wave per node --------------
__global__ __launch_bounds__(256) void k_nqk(const float* __restrict__ x,
    const float* __restrict__ wq, const float* __restrict__ wk,
    float* __restrict__ nq, float* __restrict__ nk, ushort* __restrict__ xb) {
  int w = threadIdx.x >> 6, lane = threadIdx.x & 63;
  int n = blockIdx.x * 4 + w;
  if (n >= NN) return;
  float x0 = x[(size_t)n * DD + lane];
  float x1 = x[(size_t)n * DD + 64 + lane];
  xb[(size_t)n * DD + lane] = f2b(x0);
  xb[(size_t)n * DD + 64 + lane] = f2b(x1);
  for (int r = 0; r < RR; ++r) {
    float pq = x0 * wq[r * DD + lane] + x1 * wq[r * DD + 64 + lane];
    float pk = x0 * wk[r * DD + lane] + x1 * wk[r * DD + 64 + lane];
    #pragma unroll
    for (int m = 32; m > 0; m >>= 1) { pq += __shfl_xor(pq, m); pk += __shfl_xor(pk, m); }
    if (lane == 0) { nq[r * NN + n] = pq; nk[r * NN + n] = pk; }
  }
}

// ---------------- bucket histogram (LDS-staged) ----------------------------
__global__ __launch_bounds__(256) void k_histb(const int* __restrict__ ei,
                                               int* __restrict__ bcnt) {
  __shared__ int lh[NB];
  int tid = threadIdx.x;
  if (tid < NB) lh[tid] = 0;
  __syncthreads();
  int e = blockIdx.x * 1024 + tid;
  #pragma unroll
  for (int k = 0; k < 4; ++k, e += 256)
    if (e < NE) atomicAdd(&lh[ei[NE + e] >> 8], 1);
  __syncthreads();
  if (tid < NB && lh[tid]) atomicAdd(&bcnt[tid], lh[tid]);
}

// ---------------- bucket base scan + zero cursors --------------------------
__global__ __launch_bounds__(64) void k_bscan(const int* __restrict__ bcnt,
    int* __restrict__ bbase, int* __restrict__ bcur) {
  if (threadIdx.x == 0) {
    int run = 0;
    for (int i = 0; i < NB; ++i) { bbase[i] = run; bcur[i] = 0; run += bcnt[i]; }
  }
}

// ------- partition edges into bucket-grouped bedge (s|r<<16|dlo<<19) -------
__global__ __launch_bounds__(256) void k_bscatter(const int* __restrict__ ei,
    const int* __restrict__ et, const int* __restrict__ bbase,
    int* __restrict__ bcur, unsigned* __restrict__ bedge) {
  __shared__ unsigned sval[TILE];
  __shared__ unsigned char sbkt[TILE];
  __shared__ int lh[NB], lbase[NB], lcur[NB];
  int tid = threadIdx.x;
  int e0 = blockIdx.x * TILE;
  int lim = NE - e0; if (lim > TILE) lim = TILE;
  for (int i = tid; i < NB; i += 256) lh[i] = 0;
  __syncthreads();
  for (int i = tid; i < lim; i += 256) {
    int e = e0 + i;
    int d = ei[NE + e];
    sval[i] = (unsigned)ei[e] | ((unsigned)et[e] << 16) | ((unsigned)(d & 255) << 19);
    sbkt[i] = (unsigned char)(d >> 8);
    atomicAdd(&lh[d >> 8], 1);
  }
  __syncthreads();
  for (int i = tid; i < NB; i += 256) {
    int c = lh[i];
    lbase[i] = c ? atomicAdd(&bcur[i], c) : 0;
    lcur[i] = 0;
  }
  __syncthreads();
  for (int i = tid; i < lim; i += 256) {
    int b = sbkt[i];
    int pos = bbase[b] + lbase[b] + atomicAdd(&lcur[b], 1);
    bedge[pos] = sval[i];
  }
}

// ------- per-bucket: deg, offs, CSR placement (L2-local writes) ------------
__global__ __launch_bounds__(256) void k_bfinal(const unsigned* __restrict__ bedge,
    const int* __restrict__ bbase, const int* __restrict__ bcnt,
    int* __restrict__ deg, int* __restrict__ offs, int* __restrict__ rec_src) {
  __shared__ int lh[256], sc[256], lcur[256];
  int b = blockIdx.x, tid = threadIdx.x;
  int base = bbase[b], cnt = bcnt[b];
  lh[tid] = 0;
  __syncthreads();
  for (int i = tid; i < cnt; i += 256)
    atomicAdd(&lh[(bedge[base + i] >> 19) & 255], 1);
  __syncthreads();
  int v = lh[tid];
  sc[tid] = v;
  __syncthreads();
  for (int off = 1; off < 256; off <<= 1) {
    int u = (tid >= off) ? sc[tid - off] : 0;
    __syncthreads();
    sc[tid] += u;
    __syncthreads();
  }
  int excl = sc[tid] - v;
  int n = (b << 8) + tid;
  if (n < NN) { deg[n] = v; offs[n] = base + excl; }
  lcur[tid] = base + excl;
  __syncthreads();
  for (int i = tid; i < cnt; i += 256) {
    unsigned r = bedge[base + i];
    int pos = atomicAdd(&lcur[(r >> 19) & 255], 1);
    rec_src[pos] = (int)(r & 0x7FFFFu);
  }
}

// ------- fused online-softmax aggregation of RAW x rows into z -------------
// one 64-lane wave per node; lane owns cols {lane*2, lane*2+1} for all 6 rels
#define PROC(P, SR, V) { \
  float f0 = bflo(V), f1 = bfhi(V); \
  switch ((SR) >> 16) { \
    case 0: acc00 += (P)*f0; acc01 += (P)*f1; break; \
    case 1: acc10 += (P)*f0; acc11 += (P)*f1; break; \
    case 2: acc20 += (P)*f0; acc21 += (P)*f1; break; \
    case 3: acc30 += (P)*f0; acc31 += (P)*f1; break; \
    case 4: acc40 += (P)*f0; acc41 += (P)*f1; break; \
    default: acc50 += (P)*f0; acc51 += (P)*f1; break; } }

#define RESCALE(SC) { float _s=(SC); ssum*=_s; \
  acc00*=_s; acc01*=_s; acc10*=_s; acc11*=_s; acc20*=_s; acc21*=_s; \
  acc30*=_s; acc31*=_s; acc40*=_s; acc41*=_s; acc50*=_s; acc51*=_s; }

__global__ __launch_bounds__(256) void k_aggz(const ushort* __restrict__ xb,
    const int* __restrict__ offs, const int* __restrict__ deg,
    const int* __restrict__ rec_src, const float* __restrict__ nq,
    const float* __restrict__ nk, ushort* __restrict__ z,
    float* __restrict__ mrec, float* __restrict__ irec) {
  int w = threadIdx.x >> 6, lane = threadIdx.x & 63;
  int n = blockIdx.x * 4 + w;
  if (n >= NN) return;
  int base = offs[n], cnt = deg[n];

  float m = -1e30f, ssum = 0.f;
  float acc00=0,acc01=0,acc10=0,acc11=0,acc20=0,acc21=0;
  float acc30=0,acc31=0,acc40=0,acc41=0,acc50=0,acc51=0;

  int j = 0;
  for (; j + 3 < cnt; j += 4) {
    int sr1 = rec_src[base + j],     sr2 = rec_src[base + j + 1];
    int sr3 = rec_src[base + j + 2], sr4 = rec_src[base + j + 3];
    int s1 = sr1 & 0xFFFF, r1 = sr1 >> 16;
    int s2 = sr2 & 0xFFFF, r2 = sr2 >> 16;
    int s3 = sr3 & 0xFFFF, r3 = sr3 >> 16;
    int s4 = sr4 & 0xFFFF, r4 = sr4 >> 16;
    unsigned v1 = *reinterpret_cast<const unsigned*>(xb + (size_t)s1 * DD + lane * 2);
    unsigned v2 = *reinterpret_cast<const unsigned*>(xb + (size_t)s2 * DD + lane * 2);
    unsigned v3 = *reinterpret_cast<const unsigned*>(xb + (size_t)s3 * DD + lane * 2);
    unsigned v4 = *reinterpret_cast<const unsigned*>(xb + (size_t)s4 * DD + lane * 2);
    float l1 = nq[r1 * NN + n] + nk[r1 * NN + s1];
    float l2 = nq[r2 * NN + n] + nk[r2 * NN + s2];
    float l3 = nq[r3 * NN + n] + nk[r3 * NN + s3];
    float l4 = nq[r4 * NN + n] + nk[r4 * NN + s4];
    l1 = l1 > 0.f ? l1 : NEG * l1;  l2 = l2 > 0.f ? l2 : NEG * l2;
    l3 = l3 > 0.f ? l3 : NEG * l3;  l4 = l4 > 0.f ? l4 : NEG * l4;
    float pm = fmaxf(fmaxf(l1, l2), fmaxf(l3, l4));
    if (pm > m + 8.f) { RESCALE(__expf(m - pm)); m = pm; }   // defer-max (T13)
    float p1 = __expf(l1 - m), p2 = __expf(l2 - m);
    float p3 = __expf(l3 - m), p4 = __expf(l4 - m);
    ssum += (p1 + p2) + (p3 + p4);
    PROC(p1, sr1, v1); PROC(p2, sr2, v2); PROC(p3, sr3, v3); PROC(p4, sr4, v4);
  }
  for (; j < cnt; ++j) {
    int sr1 = rec_src[base + j];
    int s1 = sr1 & 0xFFFF, r1 = sr1 >> 16;
    unsigned v1 = *reinterpret_cast<const unsigned*>(xb + (size_t)s1 * DD + lane * 2);
    float l1 = nq[r1 * NN + n] + nk[r1 * NN + s1];
    l1 = l1 > 0.f ? l1 : NEG * l1;
    if (l1 > m + 8.f) { RESCALE(__expf(m - l1)); m = l1; }
    float p1 = __expf(l1 - m);
    ssum += p1;
    PROC(p1, sr1, v1);
  }

  float inv = 1.f / (ssum + 1e-16f);
  ushort* zp = z + (size_t)n * (RR * DD) + lane * 2;
  unsigned pk;
  pk = (unsigned)f2b(acc00 * inv) | ((unsigned)f2b(acc01 * inv) << 16);
  *reinterpret_cast<unsigned*>(zp + 0 * DD) = pk;
  pk = (unsigned)f2b(acc10 * inv) | ((unsigned)f2b(acc11 * inv) << 16);
  *reinterpret_cast<unsigned*>(zp + 1 * DD) = pk;
  pk = (unsigned)f2b(acc20 * inv) | ((unsigned)f2b(acc21 * inv) << 16);
  *reinterpret_cast<unsigned*>(zp + 2 * DD) = pk;
  pk = (unsigned)f2b(acc30 * inv) | ((unsigned)f2b(acc31 * inv) << 16);
  *reinterpret_cast<unsigned*>(zp + 3 * DD) = pk;
  pk = (unsigned)f2b(acc40 * inv) | ((unsigned)f2b(acc41 * inv) << 16);
  *reinterpret_cast<unsigned*>(zp + 4 * DD) = pk;
  pk = (unsigned)f2b(acc50 * inv) | ((unsigned)f2b(acc51 * inv) << 16);
  *reinterpret_cast<unsigned*>(zp + 5 * DD) = pk;

  if (lane == 0) { mrec[n] = m; irec[n] = inv; }
}

// ------- out = x + bias + z @ W_cat  (MFMA, K=768) --------------------------
__global__ __launch_bounds__(256) void k_gemm2(const ushort* __restrict__ z,
    const ushort* __restrict__ wp2, const float* __restrict__ x,
    const float* __restrict__ bias, float* __restrict__ out) {
  int tid = threadIdx.x;
  int w = tid >> 6, l = tid & 63;
  int wrow = w & 1, wcol = w >> 1;
  int row0 = blockIdx.x * 64 + wrow * 32;
  int lr = l & 15, lg = l >> 4;

  f32x4 acc[2][4];
  #pragma unroll
  for (int i = 0; i < 2; ++i)
    #pragma unroll
    for (int c = 0; c < 4; ++c) acc[i][c] = (f32x4){0.f, 0.f, 0.f, 0.f};

  int rA0 = row0 + lr;       rA0 = rA0 < NN ? rA0 : NN - 1;
  int rA1 = row0 + 16 + lr;  rA1 = rA1 < NN ? rA1 : NN - 1;
  const ushort* a0p = z + (size_t)rA0 * (RR * DD) + lg * 8;
  const ushort* a1p = z + (size_t)rA1 * (RR * DD) + lg * 8;

  #pragma unroll 4
  for (int ks = 0; ks < KS2; ++ks) {
    short8 a0 = *reinterpret_cast<const short8*>(a0p + ks * 32);
    short8 a1 = *reinterpret_cast<const short8*>(a1p + ks * 32);
    #pragma unroll
    for (int cfl = 0; cfl < 4; ++cfl) {
      const ushort* bp = wp2 + ((size_t)((wcol * 4 + cfl) * KS2 + ks) * 64 + l) * 8;
      short8 b = *reinterpret_cast<const short8*>(bp);
      acc[0][cfl] = __builtin_amdgcn_mfma_f32_16x16x32_bf16(a0, b, acc[0][cfl], 0, 0, 0);
      acc[1][cfl] = __builtin_amdgcn_mfma_f32_16x16x32_bf16(a1, b, acc[1][cfl], 0, 0, 0);
    }
  }

  #pragma unroll
  for (int cfl = 0; cfl < 4; ++cfl) {
    int col = wcol * 64 + cfl * 16 + lr;
    float bb = bias[col];
    #pragma unroll
    for (int rf = 0; rf < 2; ++rf) {
      int rowb = row0 + rf * 16 + lg * 4;
      #pragma unroll
      for (int jj = 0; jj < 4; ++jj) {
        int row = rowb + jj;
        if (row < NN) {
          size_t o = (size_t)row * DD + col;
          out[o] = x[o] + bb + acc[rf][cfl][jj];
        }
      }
    }
  }
}

// ---------------- alpha in original edge order (coalesced write) -----------
__global__ __launch_bounds__(256) void k_alpha(const int* __restrict__ ei,
    const int* __restrict__ et, const float* __restrict__ nq,
    const float* __restrict__ nk, const float* __restrict__ mrec,
    const float* __restrict__ irec, float* __restrict__ alpha) {
  int e = blockIdx.x * 256 + threadIdx.x;
  if (e >= NE) return;
  int s = ei[e], d = ei[NE + e], r = et[e];
  float l = nq[r * NN + d] + nk[r * NN + s];
  l = l > 0.f ? l : NEG * l;
  alpha[e] = __expf(l - mrec[d]) * irec[d];
}

extern "C" void kernel_launch(void* const* d_in, const int* in_sizes, int n_in,
                              void* d_out, int out_size, void* d_ws, size_t ws_size,
                              hipStream_t stream) {
  const float* x    = (const float*)d_in[0];
  const int*   ei   = (const int*)d_in[1];
  const int*   et   = (const int*)d_in[2];
  const float* W    = (const float*)d_in[3];
  const float* qv   = (const float*)d_in[4];
  const float* kv   = (const float*)d_in[5];
  const float* bias = (const float*)d_in[6];

  float* out   = (float*)d_out;              // [NN*DD]
  float* alpha = out + (size_t)NN * DD;      // [NE]

  char* p = (char*)d_ws;
  ushort*   z     = (ushort*)p;   p += (size_t)NN * RR * DD * sizeof(ushort); // 76.8 MB
  unsigned* bedge = (unsigned*)z;  // alias: bedge dead before z is written
  ushort*   xb    = (ushort*)p;   p += (size_t)NN * DD * sizeof(ushort);      // 12.8 MB
  float*    nq    = (float*)p;    p += (size_t)RR * NN * sizeof(float);
  float*    nk    = (float*)p;    p += (size_t)RR * NN * sizeof(float);
  float*    wq    = (float*)p;    p += RR * DD * sizeof(float);
  float*    wk    = (float*)p;    p += RR * DD * sizeof(float);
  int*      deg   = (int*)p;      p += NN * sizeof(int);
  int*      offs  = (int*)p;      p += NN * sizeof(int);
  float*    mrec  = (float*)p;    p += NN * sizeof(float);
  float*    irec  = (float*)p;    p += NN * sizeof(float);
  int*      bcnt  = (int*)p;      p += NB * sizeof(int);
  int*      bbase = (int*)p;      p += NB * sizeof(int);
  int*      bcur  = (int*)p;      p += NB * sizeof(int);
  p = (char*)(((uintptr_t)p + 15) & ~(uintptr_t)15);
  int*      rec_src = (int*)p;    p += (size_t)NE * sizeof(int);              // 4.8 MB
  ushort*   wp2   = (ushort*)p;   p += (size_t)8 * KS2 * 64 * 8 * sizeof(ushort); // 196 KB

  k_prep<<<48, 256, 0, stream>>>(W, qv, kv, wq, wk, wp2, bcnt);
  k_nqk<<<(NN + 3) / 4, 256, 0, stream>>>(x, wq, wk, nq, nk, xb);
  k_histb<<<(NE + 1023) / 1024, 256, 0, stream>>>(ei, bcnt);
  k_bscan<<<1, 64, 0, stream>>>(bcnt, bbase, bcur);
  k_bscatter<<<(NE + TILE - 1) / TILE, 256, 0, stream>>>(ei, et, bbase, bcur, bedge);
  k_bfinal<<<NB, 256, 0, stream>>>(bedge, bbase, bcnt, deg, offs, rec_src);
  k_aggz<<<(NN + 3) / 4, 256, 0, stream>>>(xb, offs, deg, rec_src, nq, nk,
                                           z, mrec, irec);
  k_gemm2<<<(NN + 63) / 64, 256, 0, stream>>>(z, wp2, x, bias, out);
  k_alpha<<<(NE + 255) / 256, 256, 0, stream>>>(ei, et, nq, nk, mrec, irec, alpha);
}

// Round 7
// 236.853 us; speedup vs baseline: 1.2487x; 1.2487x over previous
//
#include <hip/hip_runtime.h>
#include <hip/hip_bf16.h>
#include <cstdint>

#define NN 50000
#define NE 1200000
#define DD 128
#define RR 6
#define NEG 0.2f
#define NB 196          // ceil(NN/256) buckets of 256 nodes
#define TILE 4096       // edges per k_bscatter block

typedef __hip_bfloat16 bf16;
typedef __attribute__((ext_vector_type(8))) short short8;
typedef __attribute__((ext_vector_type(4))) float f32x4;

__device__ __forceinline__ float bflo(unsigned u) { return __uint_as_float((u & 0xFFFFu) << 16); }
__device__ __forceinline__ float bfhi(unsigned u) { return __uint_as_float(u & 0xFFFF0000u); }
__device__ __forceinline__ ushort f2b(float v) {  // f32 -> bf16 RTNE
  unsigned b = __float_as_uint(v);
  return (ushort)((b + 0x7FFFu + ((b >> 16) & 1u)) >> 16);
}

// ------- prep: bcnt zero + wq/wk + pack per-relation W into B-frags --------
__global__ __launch_bounds__(256) void k_prep(const float* __restrict__ W,
    const float* __restrict__ qv, const float* __restrict__ kv,
    float* __restrict__ wq, float* __restrict__ wk,
    ushort* __restrict__ wp, int* __restrict__ bcnt) {
  int t = blockIdx.x * 256 + threadIdx.x;
  if (t < NB) bcnt[t] = 0;
  if (t < RR * DD) {
    int r = t / DD, d = t % DD;
    const float* row = W + ((size_t)r * DD + d) * DD;
    float aq = 0.f, ak = 0.f;
    for (int o = 0; o < DD; ++o) { float w = row[o]; aq += w * qv[o]; ak += w * kv[o]; }
    wq[t] = aq; wk[t] = ak;
  }
  // 12288 records: wp[((r*8+cf)*4+ks)*64+lane][e] = W_r[ks*32+8*(lane>>4)+e][cf*16+(lane&15)]
  {
    int lane = t & 63;
    int ks = (t >> 6) & 3;
    int cf = (t >> 8) & 7;
    int r = t >> 11;
    if (r < RR) {
      int col = cf * 16 + (lane & 15);
      int k0 = ks * 32 + (lane >> 4) * 8;
      ushort* dst = wp + (size_t)t * 8;
      #pragma unroll
      for (int e = 0; e < 8; ++e)
        dst[e] = f2b(W[((size_t)r * DD + (k0 + e)) * DD + col]);
    }
  }
}

// ---------------- nq[r,n] = x[n]·wq[r], one wave per node -----------------
__global__ __launch_bounds__(256) void k_nqk(const float* __restrict__ x,
    const float* __restrict__ wq, const float* __restrict__ wk,
    float* __restrict__ nq, float* __restrict__ nk) {
  int w = threadIdx.x >> 6, lane = threadIdx.x & 63;
  int n = blockIdx.x * 4 + w;
  if (n >= NN) return;
  float x0 = x[(size_t)n * DD + lane];
  float x1 = x[(size_t)n * DD + 64 + lane];
  for (int r = 0; r < RR; ++r) {
    float pq = x0 * wq[r * DD + lane] + x1 * wq[r * DD + 64 + lane];
    float pk = x0 * wk[r * DD + lane] + x1 * wk[r * DD + 64 + lane];
    #pragma unroll
    for (int m = 32; m > 0; m >>= 1) { pq += __shfl_xor(pq, m); pk += __shfl_xor(pk, m); }
    if (lane == 0) { nq[r * NN + n] = pq; nk[r * NN + n] = pk; }
  }
}

// ---------------- hx[r,n,o] via bf16 MFMA; A regs reused over relations ---
__global__ __launch_bounds__(256) void k_gemm(const float* __restrict__ x,
    const ushort* __restrict__ wp, ushort* __restrict__ hx) {
  int tid = threadIdx.x;
  int w = tid >> 6, l = tid & 63;
  int wrow = w & 1, wcol = w >> 1;
  int row0 = blockIdx.x * 64 + wrow * 32;
  int lr = l & 15, lg = l >> 4;

  short8 af[2][4];
  #pragma unroll
  for (int rf = 0; rf < 2; ++rf) {
    int row = row0 + rf * 16 + lr;
    row = row < NN ? row : NN - 1;
    const float* src = x + (size_t)row * DD + lg * 8;
    #pragma unroll
    for (int ks = 0; ks < 4; ++ks) {
      float4 u0 = *reinterpret_cast<const float4*>(src + ks * 32);
      float4 u1 = *reinterpret_cast<const float4*>(src + ks * 32 + 4);
      short8 a;
      a[0] = (short)f2b(u0.x); a[1] = (short)f2b(u0.y);
      a[2] = (short)f2b(u0.z); a[3] = (short)f2b(u0.w);
      a[4] = (short)f2b(u1.x); a[5] = (short)f2b(u1.y);
      a[6] = (short)f2b(u1.z); a[7] = (short)f2b(u1.w);
      af[rf][ks] = a;
    }
  }

  for (int r = 0; r < RR; ++r) {
    #pragma unroll
    for (int cfl = 0; cfl < 4; ++cfl) {
      int cfg = wcol * 4 + cfl;
      const ushort* bp = wp + (((size_t)(r * 8 + cfg) * 4) * 64 + l) * 8;
      short8 b0 = *reinterpret_cast<const short8*>(bp);
      short8 b1 = *reinterpret_cast<const short8*>(bp + 512);
      short8 b2 = *reinterpret_cast<const short8*>(bp + 1024);
      short8 b3 = *reinterpret_cast<const short8*>(bp + 1536);
      f32x4 acc0 = {0.f, 0.f, 0.f, 0.f};
      f32x4 acc1 = {0.f, 0.f, 0.f, 0.f};
      acc0 = __builtin_amdgcn_mfma_f32_16x16x32_bf16(af[0][0], b0, acc0, 0, 0, 0);
      acc1 = __builtin_amdgcn_mfma_f32_16x16x32_bf16(af[1][0], b0, acc1, 0, 0, 0);
      acc0 = __builtin_amdgcn_mfma_f32_16x16x32_bf16(af[0][1], b1, acc0, 0, 0, 0);
      acc1 = __builtin_amdgcn_mfma_f32_16x16x32_bf16(af[1][1], b1, acc1, 0, 0, 0);
      acc0 = __builtin_amdgcn_mfma_f32_16x16x32_bf16(af[0][2], b2, acc0, 0, 0, 0);
      acc1 = __builtin_amdgcn_mfma_f32_16x16x32_bf16(af[1][2], b2, acc1, 0, 0, 0);
      acc0 = __builtin_amdgcn_mfma_f32_16x16x32_bf16(af[0][3], b3, acc0, 0, 0, 0);
      acc1 = __builtin_amdgcn_mfma_f32_16x16x32_bf16(af[1][3], b3, acc1, 0, 0, 0);

      int col = cfg * 16 + lr;
      #pragma unroll
      for (int rf = 0; rf < 2; ++rf) {
        int rowb = row0 + rf * 16 + lg * 4;
        f32x4 ac = rf ? acc1 : acc0;
        #pragma unroll
        for (int j = 0; j < 4; ++j) {
          int rowz = rowb + j;
          if (rowz < NN)
            hx[((size_t)r * NN + rowz) * DD + col] = f2b(ac[j]);
        }
      }
    }
  }
}

// ---------------- bucket histogram (LDS-staged) ----------------------------
__global__ __launch_bounds__(256) void k_histb(const int* __restrict__ ei,
                                               int* __restrict__ bcnt) {
  __shared__ int lh[NB];
  int tid = threadIdx.x;
  if (tid < NB) lh[tid] = 0;
  __syncthreads();
  int e = blockIdx.x * 1024 + tid;
  #pragma unroll
  for (int k = 0; k < 4; ++k, e += 256)
    if (e < NE) atomicAdd(&lh[ei[NE + e] >> 8], 1);
  __syncthreads();
  if (tid < NB && lh[tid]) atomicAdd(&bcnt[tid], lh[tid]);
}

// ---------------- bucket base scan + zero cursors --------------------------
__global__ __launch_bounds__(64) void k_bscan(const int* __restrict__ bcnt,
    int* __restrict__ bbase, int* __restrict__ bcur) {
  if (threadIdx.x == 0) {
    int run = 0;
    for (int i = 0; i < NB; ++i) { bbase[i] = run; bcur[i] = 0; run += bcnt[i]; }
  }
}

// ------- partition edges into bucket-grouped bedge (s|r<<16|dlo<<19) -------
__global__ __launch_bounds__(256) void k_bscatter(const int* __restrict__ ei,
    const int* __restrict__ et, const int* __restrict__ bbase,
    int* __restrict__ bcur, unsigned* __restrict__ bedge) {
  __shared__ unsigned sval[TILE];
  __shared__ unsigned char sbkt[TILE];
  __shared__ int lh[NB], lbase[NB], lcur[NB];
  int tid = threadIdx.x;
  int e0 = blockIdx.x * TILE;
  int lim = NE - e0; if (lim > TILE) lim = TILE;
  for (int i = tid; i < NB; i += 256) lh[i] = 0;
  __syncthreads();
  for (int i = tid; i < lim; i += 256) {
    int e = e0 + i;
    int d = ei[NE + e];
    sval[i] = (unsigned)ei[e] | ((unsigned)et[e] << 16) | ((unsigned)(d & 255) << 19);
    sbkt[i] = (unsigned char)(d >> 8);
    atomicAdd(&lh[d >> 8], 1);
  }
  __syncthreads();
  for (int i = tid; i < NB; i += 256) {
    int c = lh[i];
    lbase[i] = c ? atomicAdd(&bcur[i], c) : 0;
    lcur[i] = 0;
  }
  __syncthreads();
  for (int i = tid; i < lim; i += 256) {
    int b = sbkt[i];
    int pos = bbase[b] + lbase[b] + atomicAdd(&lcur[b], 1);
    bedge[pos] = sval[i];
  }
}

// ------- per-bucket: deg, offs, CSR placement (L2-local writes) ------------
__global__ __launch_bounds__(256) void k_bfinal(const unsigned* __restrict__ bedge,
    const int* __restrict__ bbase, const int* __restrict__ bcnt,
    int* __restrict__ deg, int* __restrict__ offs, int* __restrict__ rec_src) {
  __shared__ int lh[256], sc[256], lcur[256];
  int b = blockIdx.x, tid = threadIdx.x;
  int base = bbase[b], cnt = bcnt[b];
  lh[tid] = 0;
  __syncthreads();
  for (int i = tid; i < cnt; i += 256)
    atomicAdd(&lh[(bedge[base + i] >> 19) & 255], 1);
  __syncthreads();
  int v = lh[tid];
  sc[tid] = v;
  __syncthreads();
  for (int off = 1; off < 256; off <<= 1) {
    int u = (tid >= off) ? sc[tid - off] : 0;
    __syncthreads();
    sc[tid] += u;
    __syncthreads();
  }
  int excl = sc[tid] - v;
  int n = (b << 8) + tid;
  if (n < NN) { deg[n] = v; offs[n] = base + excl; }
  lcur[tid] = base + excl;
  __syncthreads();
  for (int i = tid; i < cnt; i += 256) {
    unsigned r = bedge[base + i];
    int pos = atomicAdd(&lcur[(r >> 19) & 255], 1);
    rec_src[pos] = (int)(r & 0x7FFFFu);   // s | r<<16
  }
}

// ------- fused online-softmax gather-aggregate (defer-max, 4-edge unroll) --
__global__ __launch_bounds__(256) void k_agg(const float* __restrict__ x,
    const float* __restrict__ bias, const int* __restrict__ offs,
    const int* __restrict__ deg, const int* __restrict__ rec_src,
    const float* __restrict__ nq, const float* __restrict__ nk,
    const bf16* __restrict__ hx, float* __restrict__ out,
    float* __restrict__ mrec, float* __restrict__ irec) {
  int g = threadIdx.x >> 5, lane = threadIdx.x & 31;
  int n = blockIdx.x * 8 + g;
  if (n >= NN) return;
  int base = offs[n], cnt = deg[n];

  float m = -1e30f, ssum = 0.f;
  float a0 = 0.f, a1 = 0.f, a2 = 0.f, a3 = 0.f;

  int j = 0;
  for (; j + 3 < cnt; j += 4) {
    int sr1 = rec_src[base + j],     sr2 = rec_src[base + j + 1];
    int sr3 = rec_src[base + j + 2], sr4 = rec_src[base + j + 3];
    int s1 = sr1 & 0xFFFF, r1 = sr1 >> 16;
    int s2 = sr2 & 0xFFFF, r2 = sr2 >> 16;
    int s3 = sr3 & 0xFFFF, r3 = sr3 >> 16;
    int s4 = sr4 & 0xFFFF, r4 = sr4 >> 16;
    uint2 q1 = *reinterpret_cast<const uint2*>(hx + ((size_t)r1 * NN + s1) * DD + lane * 4);
    uint2 q2 = *reinterpret_cast<const uint2*>(hx + ((size_t)r2 * NN + s2) * DD + lane * 4);
    uint2 q3 = *reinterpret_cast<const uint2*>(hx + ((size_t)r3 * NN + s3) * DD + lane * 4);
    uint2 q4 = *reinterpret_cast<const uint2*>(hx + ((size_t)r4 * NN + s4) * DD + lane * 4);
    float l1 = nq[r1 * NN + n] + nk[r1 * NN + s1];
    float l2 = nq[r2 * NN + n] + nk[r2 * NN + s2];
    float l3 = nq[r3 * NN + n] + nk[r3 * NN + s3];
    float l4 = nq[r4 * NN + n] + nk[r4 * NN + s4];
    l1 = l1 > 0.f ? l1 : NEG * l1;  l2 = l2 > 0.f ? l2 : NEG * l2;
    l3 = l3 > 0.f ? l3 : NEG * l3;  l4 = l4 > 0.f ? l4 : NEG * l4;
    float pm = fmaxf(fmaxf(l1, l2), fmaxf(l3, l4));
    if (pm > m + 8.f) {              // defer-max (T13): rescale rarely
      float sc = __expf(m - pm);
      ssum *= sc; a0 *= sc; a1 *= sc; a2 *= sc; a3 *= sc;
      m = pm;
    }
    float p1 = __expf(l1 - m), p2 = __expf(l2 - m);
    float p3 = __expf(l3 - m), p4 = __expf(l4 - m);
    ssum += (p1 + p2) + (p3 + p4);
    a0 += p1 * bflo(q1.x) + p2 * bflo(q2.x) + p3 * bflo(q3.x) + p4 * bflo(q4.x);
    a1 += p1 * bfhi(q1.x) + p2 * bfhi(q2.x) + p3 * bfhi(q3.x) + p4 * bfhi(q4.x);
    a2 += p1 * bflo(q1.y) + p2 * bflo(q2.y) + p3 * bflo(q3.y) + p4 * bflo(q4.y);
    a3 += p1 * bfhi(q1.y) + p2 * bfhi(q2.y) + p3 * bfhi(q3.y) + p4 * bfhi(q4.y);
  }
  for (; j < cnt; ++j) {
    int sr1 = rec_src[base + j];
    int s1 = sr1 & 0xFFFF, r1 = sr1 >> 16;
    uint2 q1 = *reinterpret_cast<const uint2*>(hx + ((size_t)r1 * NN + s1) * DD + lane * 4);
    float l1 = nq[r1 * NN + n] + nk[r1 * NN + s1];
    l1 = l1 > 0.f ? l1 : NEG * l1;
    if (l1 > m + 8.f) {
      float sc = __expf(m - l1);
      ssum *= sc; a0 *= sc; a1 *= sc; a2 *= sc; a3 *= sc;
      m = l1;
    }
    float p1 = __expf(l1 - m);
    ssum += p1;
    a0 += p1 * bflo(q1.x);
    a1 += p1 * bfhi(q1.x);
    a2 += p1 * bflo(q1.y);
    a3 += p1 * bfhi(q1.y);
  }

  float inv = 1.f / (ssum + 1e-16f);
  size_t o = (size_t)n * DD + lane * 4;
  float4 xb = *reinterpret_cast<const float4*>(x + o);
  float4 bb = *reinterpret_cast<const float4*>(bias + lane * 4);
  float4 res;
  res.x = xb.x + bb.x + a0 * inv;
  res.y = xb.y + bb.y + a1 * inv;
  res.z = xb.z + bb.z + a2 * inv;
  res.w = xb.w + bb.w + a3 * inv;
  *reinterpret_cast<float4*>(out + o) = res;

  if (lane == 0) { mrec[n] = m; irec[n] = inv; }
}

// ---------------- alpha in original edge order (coalesced write) -----------
__global__ __launch_bounds__(256) void k_alpha(const int* __restrict__ ei,
    const int* __restrict__ et, const float* __restrict__ nq,
    const float* __restrict__ nk, const float* __restrict__ mrec,
    const float* __restrict__ irec, float* __restrict__ alpha) {
  int e = blockIdx.x * 256 + threadIdx.x;
  if (e >= NE) return;
  int s = ei[e], d = ei[NE + e], r = et[e];
  float l = nq[r * NN + d] + nk[r * NN + s];
  l = l > 0.f ? l : NEG * l;
  alpha[e] = __expf(l - mrec[d]) * irec[d];
}

extern "C" void kernel_launch(void* const* d_in, const int* in_sizes, int n_in,
                              void* d_out, int out_size, void* d_ws, size_t ws_size,
                              hipStream_t stream) {
  const float* x    = (const float*)d_in[0];
  const int*   ei   = (const int*)d_in[1];
  const int*   et   = (const int*)d_in[2];
  const float* W    = (const float*)d_in[3];
  const float* qv   = (const float*)d_in[4];
  const float* kv   = (const float*)d_in[5];
  const float* bias = (const float*)d_in[6];

  float* out   = (float*)d_out;              // [NN*DD]
  float* alpha = out + (size_t)NN * DD;      // [NE]

  char* p = (char*)d_ws;
  bf16*  hx      = (bf16*)p;    p += (size_t)RR * NN * DD * sizeof(bf16); // 76.8 MB
  float* nq      = (float*)p;   p += (size_t)RR * NN * sizeof(float);
  float* nk      = (float*)p;   p += (size_t)RR * NN * sizeof(float);
  float* wq      = (float*)p;   p += RR * DD * sizeof(float);
  float* wk      = (float*)p;   p += RR * DD * sizeof(float);
  int*   deg     = (int*)p;     p += NN * sizeof(int);
  int*   offs    = (int*)p;     p += NN * sizeof(int);
  float* mrec    = (float*)p;   p += NN * sizeof(float);
  float* irec    = (float*)p;   p += NN * sizeof(float);
  int*   bcnt    = (int*)p;     p += NB * sizeof(int);
  int*   bbase   = (int*)p;     p += NB * sizeof(int);
  int*   bcur    = (int*)p;     p += NB * sizeof(int);
  p = (char*)(((uintptr_t)p + 15) & ~(uintptr_t)15);
  unsigned* bedge = (unsigned*)p; p += (size_t)NE * sizeof(unsigned);     // 4.8 MB
  int*   rec_src = (int*)p;     p += (size_t)NE * sizeof(int);            // 4.8 MB
  ushort* wp     = (ushort*)p;  p += (size_t)RR * 8 * 4 * 64 * 8 * sizeof(ushort); // 196 KB

  k_prep<<<48, 256, 0, stream>>>(W, qv, kv, wq, wk, wp, bcnt);
  k_gemm<<<(NN + 63) / 64, 256, 0, stream>>>(x, wp, (ushort*)hx);
  k_nqk<<<(NN + 3) / 4, 256, 0, stream>>>(x, wq, wk, nq, nk);
  k_histb<<<(NE + 1023) / 1024, 256, 0, stream>>>(ei, bcnt);
  k_bscan<<<1, 64, 0, stream>>>(bcnt, bbase, bcur);
  k_bscatter<<<(NE + TILE - 1) / TILE, 256, 0, stream>>>(ei, et, bbase, bcur, bedge);
  k_bfinal<<<NB, 256, 0, stream>>>(bedge, bbase, bcnt, deg, offs, rec_src);
  k_agg<<<(NN + 7) / 8, 256, 0, stream>>>(x, bias, offs, deg, rec_src,
                                          nq, nk, hx, out, mrec, irec);
  k_alpha<<<(NE + 255) / 256, 256, 0, stream>>>(ei, et, nq, nk, mrec, irec, alpha);
}